// Round 17
// baseline (252.078 us; speedup 1.0000x reference)
//
#include <hip/hip_runtime.h>
#include <math.h>

#define LSEQ 4096
#define DMODEL 512
#define BB 8
#define TOPK 8
#define ML (BB * LSEQ)          // 32768 rows
#define FFT_CH 2                // channels per fft_cross block
#define NGRP (DMODEL / FFT_CH)  // 256 groups per batch
#define PPH 2052                // float2 stride of half-spectrum (2049 used, padded)

typedef unsigned short u16;
typedef unsigned int u32;
typedef float f32x4 __attribute__((ext_vector_type(4)));
typedef short s16x8 __attribute__((ext_vector_type(8)));
typedef u16 u16x8 __attribute__((ext_vector_type(8)));

__device__ __forceinline__ u16 rne_bf16(float f) {
    u32 u = __float_as_uint(f);
    return (u16)((u + 0x7FFF + ((u >> 16) & 1)) >> 16);
}

// pack 8 fp32 (two float4) -> 8 RNE bf16 as uint4
__device__ __forceinline__ uint4 cvt8(const float4 f0, const float4 f1) {
    float fs[8] = {f0.x, f0.y, f0.z, f0.w, f1.x, f1.y, f1.z, f1.w};
    u32 h[4];
#pragma unroll
    for (int p = 0; p < 4; ++p) {
        u32 u0 = __float_as_uint(fs[2 * p]);
        u32 u1 = __float_as_uint(fs[2 * p + 1]);
        u32 h0 = u0 + 0x7FFF + ((u0 >> 16) & 1);
        u32 h1 = u1 + 0x7FFF + ((u1 >> 16) & 1);
        h[p] = __builtin_amdgcn_perm(h1, h0, 0x07060302u);
    }
    return make_uint4(h[0], h[1], h[2], h[3]);
}

#if defined(__has_builtin)
#if __has_builtin(__builtin_amdgcn_global_load_lds)
#define HAVE_GLL 1
#endif
#endif

// async 16B global->LDS; lbase is WAVE-UNIFORM, HW writes lbase + lane*16B.
__device__ __forceinline__ void gload_lds16(const u16* g, u16* lbase, int lane) {
#ifdef HAVE_GLL
    __builtin_amdgcn_global_load_lds((const __attribute__((address_space(1))) void*)g,
                                     (__attribute__((address_space(3))) void*)lbase, 16, 0, 0);
#else
    *(uint4*)(lbase + lane * 8) = *(const uint4*)g;
#endif
}

// ==================== 16-pt FFT, fully unrolled DIF (output bit-reversed in regs) ====================
__device__ __forceinline__ void fft16(float (&zr)[16], float (&zi)[16]) {
    const float C1 = 0.92387953251128674f, S1 = 0.38268343236508978f, R2 = 0.70710678118654752f;
#define BF0(i, j) { float ar=zr[i],ai=zi[i],br=zr[j],bi=zi[j]; zr[i]=ar+br; zi[i]=ai+bi; zr[j]=ar-br; zi[j]=ai-bi; }
#define BFW(i, j, wr, wi) { float ar=zr[i],ai=zi[i],br=zr[j],bi=zi[j]; zr[i]=ar+br; zi[i]=ai+bi; float dr=ar-br, di=ai-bi; zr[j]=dr*(wr)-di*(wi); zi[j]=dr*(wi)+di*(wr); }
#define BFI(i, j) { float ar=zr[i],ai=zi[i],br=zr[j],bi=zi[j]; zr[i]=ar+br; zi[i]=ai+bi; float dr=ar-br, di=ai-bi; zr[j]=di; zi[j]=-dr; }
    BF0(0, 8); BFW(1, 9, C1, -S1); BFW(2, 10, R2, -R2); BFW(3, 11, S1, -C1);
    BFI(4, 12); BFW(5, 13, -S1, -C1); BFW(6, 14, -R2, -R2); BFW(7, 15, -C1, -S1);
    BF0(0, 4); BFW(1, 5, R2, -R2); BFI(2, 6); BFW(3, 7, -R2, -R2);
    BF0(8, 12); BFW(9, 13, R2, -R2); BFI(10, 14); BFW(11, 15, -R2, -R2);
    BF0(0, 2); BFI(1, 3); BF0(4, 6); BFI(5, 7);
    BF0(8, 10); BFI(9, 11); BF0(12, 14); BFI(13, 15);
    BF0(0, 1); BF0(2, 3); BF0(4, 5); BF0(6, 7);
    BF0(8, 9); BF0(10, 11); BF0(12, 13); BF0(14, 15);
#undef BF0
#undef BFW
#undef BFI
}

// 3-level radix-16 4096-pt FFT core, chained twiddles. Phys-swizzled input.
// WRITEBACK: writes ONLY the upper half-spectrum (Z[2048..4095], slots REV16[odd]) to LDS.
template <bool WRITEBACK>
__device__ __forceinline__ void fft4096_r16_core(float* __restrict__ lre, float* __restrict__ lim, int t,
                                                 float (&ozr)[16], float (&ozi)[16]) {
    constexpr int REV16[16] = {0, 8, 4, 12, 2, 10, 6, 14, 1, 9, 5, 13, 3, 11, 7, 15};
    float zr[16], zi[16];
#pragma unroll
    for (int gg = 0; gg < 16; ++gg) {
        int n = 256 * gg + t;
        int p = n ^ ((gg & 3) << 2) ^ ((gg & 1) << 4);
        zr[gg] = lre[p]; zi[gg] = lim[p];
    }
    fft16(zr, zi);
    {
        const int n1 = t >> 4;
        float w1i, w1r;
        __sincosf(-0.0245436926061702596f * (float)n1, &w1i, &w1r);  // -pi/128 * n1
        float wr = 1.f, wi = 0.f;
#pragma unroll
        for (int k0 = 0; k0 < 16; ++k0) {
            float vr = zr[REV16[k0]], vi = zi[REV16[k0]];
            if (k0) {
                float nr = wr * w1r - wi * w1i;
                wi = wr * w1i + wi * w1r;
                wr = nr;
                float tr = vr * wr - vi * wi;
                vi = vr * wi + vi * wr;
                vr = tr;
            }
            int n = 256 * k0 + t;
            int p = n ^ ((k0 & 3) << 2) ^ ((k0 & 1) << 4);
            lre[p] = vr; lim[p] = vi;
        }
    }
    __syncthreads();
    {
        const int k0 = t >> 4, n2 = t & 15;
        const int x0 = ((k0 & 3) << 2) | ((k0 & 1) << 4);
#pragma unroll
        for (int gg = 0; gg < 16; ++gg) {
            int n = 256 * k0 + 16 * gg + n2;
            zr[gg] = lre[n ^ x0]; zi[gg] = lim[n ^ x0];
        }
        fft16(zr, zi);
        float wbi, wbr, wsi, wsr;
        __sincosf(-0.00153398078788564123f * (float)(n2 * k0), &wbi, &wbr);  // -pi/2048 * n2*k0
        __sincosf(-0.0245436926061702596f * (float)n2, &wsi, &wsr);          // -pi/128 * n2
        float wr = wbr, wi = wbi;
#pragma unroll
        for (int k1 = 0; k1 < 16; ++k1) {
            float vr = zr[REV16[k1]], vi = zi[REV16[k1]];
            if (k1) {
                float nr = wr * wsr - wi * wsi;
                wi = wr * wsi + wi * wsr;
                wr = nr;
            }
            float tr = vr * wr - vi * wi;
            vi = vr * wi + vi * wr;
            vr = tr;
            int n = 256 * k0 + 16 * k1 + n2;
            lre[n ^ x0] = vr; lim[n ^ x0] = vi;
        }
    }
    __syncthreads();
    {
        const int k0 = t & 15, k1 = t >> 4;
        const int nb4 = 64 * k0 + 4 * k1;
        const int xv = (k0 & 3) | ((k0 & 1) << 2);
#pragma unroll
        for (int i = 0; i < 4; ++i) {
            int p4 = (nb4 + i) ^ xv;
            float4 fr = *(const float4*)&lre[4 * p4];
            float4 fi = *(const float4*)&lim[4 * p4];
            ozr[4 * i + 0] = fr.x; ozr[4 * i + 1] = fr.y; ozr[4 * i + 2] = fr.z; ozr[4 * i + 3] = fr.w;
            ozi[4 * i + 0] = fi.x; ozi[4 * i + 1] = fi.y; ozi[4 * i + 2] = fi.z; ozi[4 * i + 3] = fi.w;
        }
        fft16(ozr, ozi);
        if constexpr (WRITEBACK) {
            __syncthreads();  // phys reads done before natural-order overwrite
#pragma unroll
            for (int r = 1; r < 16; r += 2) {   // REV16[odd] -> Z[>=2048]
                const int k2 = REV16[r];
                lre[t + 256 * k2] = ozr[r];
                lim[t + 256 * k2] = ozi[r];
            }
            __syncthreads();
        }
    }
}

// grid: BB*NGRP blocks; block (b,g): channels d = g*FFT_CH..+1.  bf16 inputs.
__global__ __launch_bounds__(256) void fft_cross(const u16* __restrict__ Qtb,
                                                 const u16* __restrict__ Ktb,
                                                 float* __restrict__ Ppart) {
    __shared__ float lre[4096];
    __shared__ float lim[4096];
    constexpr int REV16[16] = {0, 8, 4, 12, 2, 10, 6, 14, 1, 9, 5, 13, 3, 11, 7, 15};
    const int t = threadIdx.x;
    const int b = blockIdx.x / NGRP;
    const int g = blockIdx.x % NGRP;

    float2 acc[8];
#pragma unroll
    for (int i = 0; i < 8; ++i) acc[i] = make_float2(0.f, 0.f);
    float accn = 0.f;  // Nyquist bin (j=2048), real

    const uint4* q8 = (const uint4*)(Qtb + (size_t)(g * FFT_CH) * ML + (size_t)b * LSEQ);
    const uint4* k8 = (const uint4*)(Ktb + (size_t)(g * FFT_CH) * ML + (size_t)b * LSEQ);

    uint4 pq[2], pk[2];
    pq[0] = q8[t]; pq[1] = q8[t + 256];
    pk[0] = k8[t]; pk[1] = k8[t + 256];

    for (int c = 0; c < FFT_CH; ++c) {
        __syncthreads();  // prev channel's mirror-reads done
#pragma unroll
        for (int i = 0; i < 2; ++i) {
            const int u = t + 256 * i;          // uint4 index (8 bf16)
            const uint4 vq = pq[i], vk = pk[i];
#pragma unroll
            for (int hh = 0; hh < 2; ++hh) {
                const int v = 2 * u + hh;       // float4-block index
                const int key = (v >> 6) & 15;
                const int p4 = v ^ (key & 3) ^ ((key & 1) << 2);
                const u32 w0 = hh ? vq.z : vq.x;
                const u32 w1 = hh ? vq.w : vq.y;
                float4 fa = make_float4(__uint_as_float(w0 << 16), __uint_as_float(w0 & 0xFFFF0000u),
                                        __uint_as_float(w1 << 16), __uint_as_float(w1 & 0xFFFF0000u));
                *(float4*)&lre[4 * p4] = fa;
                const u32 x0 = hh ? vk.z : vk.x;
                const u32 x1 = hh ? vk.w : vk.y;
                float4 fb4 = make_float4(__uint_as_float(x0 << 16), __uint_as_float(x0 & 0xFFFF0000u),
                                         __uint_as_float(x1 << 16), __uint_as_float(x1 & 0xFFFF0000u));
                *(float4*)&lim[4 * p4] = fb4;
            }
        }
        if (c + 1 < FFT_CH) {
            const uint4* qn = q8 + (size_t)(c + 1) * (ML / 8);
            const uint4* kn = k8 + (size_t)(c + 1) * (ML / 8);
            pq[0] = qn[t]; pq[1] = qn[t + 256];
            pk[0] = kn[t]; pk[1] = kn[t + 256];
        }
        __syncthreads();
        float ozr[16], ozi[16];
        fft4096_r16_core<true>(lre, lim, t, ozr, ozi);
        // cross-spectrum: own bins from registers, mirror bins (upper half) from LDS
#pragma unroll
        for (int i = 0; i < 8; ++i) {
            const int j = i * 256 + t;
            const int nj = (4096 - j) & 4095;
            const int r = REV16[i];
            float zfr = ozr[r], zfi = ozi[r];
            float znr, zni;
            if (j) { znr = lre[nj]; zni = lim[nj]; }
            else   { znr = zfr;     zni = zfi;     }   // Z[0] is its own mirror
            float qr = 0.5f * (zfr + znr);
            float qi = 0.5f * (zfi - zni);
            float kr = 0.5f * (zfi + zni);
            float ki = -0.5f * (zfr - znr);
            acc[i].x += qr * kr + qi * ki;
            acc[i].y += qi * kr - qr * ki;
        }
        if (t == 0) accn += ozr[1] * ozi[1];  // bin 2048 = slot REV16[8]=1 of thread 0
    }
    float2* Pp = (float2*)Ppart + (size_t)blockIdx.x * PPH;
#pragma unroll
    for (int i = 0; i < 8; ++i) Pp[i * 256 + t] = acc[i];
    if (t == 0) Pp[2048] = make_float2(accn, 0.f);
}

// ============ m97-style bf16 MFMA GEMM: A,B both bf16 -> pure global_load_lds staging ============
template <bool TOUT, bool BIAS>
__device__ __forceinline__ void gemm_bf16_body(const u16* __restrict__ A,
                                               const u16* __restrict__ B,
                                               const float* __restrict__ bias,
                                               u16* __restrict__ Cv, int lin, int tid,
                                               u16* sA, u16* sB) {
    const int t = (lin & 7) * 128 + (lin >> 3);   // XCD-chunked swizzle (1024 blocks)
    const int bm = (t >> 2) * 128;
    const int bn = (t & 3) * 128;
    const int lane = tid & 63, wid = tid >> 6;
    const int wm = wid >> 1, wn = wid & 1;
    const int l15 = lane & 15, kg = lane >> 4;

    const int srow = lane >> 3, sc = lane & 7;    // staging: 8 rows x 8 chunks per issue

    f32x4 acc[4][4] = {};

    for (int k0 = 0; k0 < 512; k0 += 64) {
        __syncthreads();  // prev compute's ds_reads done; LDS free
#pragma unroll
        for (int i = 0; i < 4; ++i) {
            const int grp = wid * 4 + i;          // 0..15, 8 rows each
            const int row = 8 * grp + srow;
            gload_lds16(A + (size_t)(bm + row) * 512 + k0 + ((sc ^ (row & 7)) << 3),
                        sA + grp * 512, lane);
        }
#pragma unroll
        for (int i = 0; i < 4; ++i) {
            const int grp = wid * 4 + i;
            const int row = 8 * grp + srow;
            gload_lds16(B + (size_t)(bn + row) * 512 + k0 + ((sc ^ (row & 7)) << 3),
                        sB + grp * 512, lane);
        }
        __syncthreads();  // drains vmcnt -> async loads landed
#pragma unroll
        for (int kk = 0; kk < 2; ++kk) {
            const int cb = kk * 4 + kg;
            s16x8 af[4], bf[4];
#pragma unroll
            for (int mi = 0; mi < 4; ++mi) {
                const int row = wm * 64 + mi * 16 + l15;
                af[mi] = *(const s16x8*)&sA[row * 64 + (((cb ^ (row & 7))) << 3)];
            }
#pragma unroll
            for (int ni = 0; ni < 4; ++ni) {
                const int row = wn * 64 + ni * 16 + l15;
                bf[ni] = *(const s16x8*)&sB[row * 64 + (((cb ^ (row & 7))) << 3)];
            }
#pragma unroll
            for (int ni = 0; ni < 4; ++ni)
#pragma unroll
                for (int mi = 0; mi < 4; ++mi)
                    acc[mi][ni] = __builtin_amdgcn_mfma_f32_16x16x32_bf16(af[mi], bf[ni], acc[mi][ni], 0, 0, 0);
        }
    }
    // epilogue (C/D layout: col = lane&15, row = (lane>>4)*4 + reg)
    if constexpr (TOUT) {
#pragma unroll
        for (int ni = 0; ni < 4; ++ni) {
            const int d = bn + wn * 64 + ni * 16 + l15;
#pragma unroll
            for (int mi = 0; mi < 4; ++mi) {
                const int rb = bm + wm * 64 + mi * 16 + (kg << 2);
                ushort4 o;
                o.x = rne_bf16(acc[mi][ni][0]); o.y = rne_bf16(acc[mi][ni][1]);
                o.z = rne_bf16(acc[mi][ni][2]); o.w = rne_bf16(acc[mi][ni][3]);
                *(ushort4*)&Cv[(size_t)d * ML + rb] = o;
            }
        }
    } else {
#pragma unroll
        for (int ni = 0; ni < 4; ++ni) {
            const int col = bn + wn * 64 + ni * 16 + l15;
            const float bvv = BIAS ? bias[col] : 0.0f;
#pragma unroll
            for (int mi = 0; mi < 4; ++mi) {
                const int rb = bm + wm * 64 + mi * 16 + (kg << 2);
#pragma unroll
                for (int r = 0; r < 4; ++r)
                    Cv[(size_t)(rb + r) * 512 + col] = rne_bf16(acc[mi][ni][r] + bvv);
            }
        }
    }
}

// ============ gemm2: Q-GEMM (1024) + V-GEMM (1024), 1:1 interleave ============
__global__ __launch_bounds__(256) void gemm2(const u16* __restrict__ Qb,
                                             const u16* __restrict__ Mh, u16* __restrict__ Qtb,
                                             const u16* __restrict__ Vb,
                                             const u16* __restrict__ Wch, const float* __restrict__ bc,
                                             u16* __restrict__ VOb) {
    __shared__ __align__(16) u16 smem[16384];  // 32 KB
    const int g = blockIdx.x;
    const int q = g >> 1, r = g & 1;
    if (r == 0)
        gemm_bf16_body<true, false>(Qb, Mh, nullptr, Qtb, q, threadIdx.x, smem, smem + 8192);
    else
        gemm_bf16_body<false, true>(Vb, Wch, bc, VOb, q, threadIdx.x, smem, smem + 8192);
}

// ============ prep_weights: M = Wq@Wk^T & Wc = Wv@Wo -> RNE bf16 [N][K]; bc (144 blocks) ============
__global__ __launch_bounds__(256) void prep_weights(const float* __restrict__ Wq, const float* __restrict__ Wk,
                                                    const float* __restrict__ Wv, const float* __restrict__ Wo,
                                                    const float* __restrict__ bvec, const float* __restrict__ bo,
                                                    u16* __restrict__ Mh, u16* __restrict__ Wch,
                                                    float* __restrict__ bc) {
    __shared__ float As[16][64];
    __shared__ float Ws[16][64];
    __shared__ float red[8][32];
    const int bx = blockIdx.x;
    const int tid = threadIdx.x;
    if (bx < 128) {
        const bool isM = bx < 64;
        const int id = bx & 63;
        const int bm = (id >> 3) * 64, bn = (id & 7) * 64;
        const int tx = tid & 15, ty = tid >> 4;
        float acc[4][4] = {};
        const int arow = tid >> 2, ak4 = tid & 3;
        const int wrow = tid >> 4, wc4 = tid & 15;
        const float* Abase = isM ? Wq : Wv;
        for (int k0 = 0; k0 < 512; k0 += 16) {
            float4 av = *(const float4*)&Abase[(size_t)(bm + arow) * 512 + k0 + ak4 * 4];
            float4 wv4;
            if (isM) wv4 = *(const float4*)&Wk[(size_t)(bn + arow) * 512 + k0 + ak4 * 4];
            else     wv4 = *(const float4*)&Wo[(size_t)(k0 + wrow) * 512 + bn + wc4 * 4];
            __syncthreads();
            As[ak4 * 4 + 0][arow] = av.x;
            As[ak4 * 4 + 1][arow] = av.y;
            As[ak4 * 4 + 2][arow] = av.z;
            As[ak4 * 4 + 3][arow] = av.w;
            if (isM) {
                Ws[ak4 * 4 + 0][arow] = wv4.x;
                Ws[ak4 * 4 + 1][arow] = wv4.y;
                Ws[ak4 * 4 + 2][arow] = wv4.z;
                Ws[ak4 * 4 + 3][arow] = wv4.w;
            } else {
                *(float4*)&Ws[wrow][wc4 * 4] = wv4;
            }
            __syncthreads();
#pragma unroll
            for (int k = 0; k < 16; ++k) {
                float4 a = *(const float4*)&As[k][ty * 4];
                float4 b = *(const float4*)&Ws[k][tx * 4];
                acc[0][0] += a.x * b.x; acc[0][1] += a.x * b.y; acc[0][2] += a.x * b.z; acc[0][3] += a.x * b.w;
                acc[1][0] += a.y * b.x; acc[1][1] += a.y * b.y; acc[1][2] += a.y * b.z; acc[1][3] += a.y * b.w;
                acc[2][0] += a.z * b.x; acc[2][1] += a.z * b.y; acc[2][2] += a.z * b.z; acc[2][3] += a.z * b.w;
                acc[3][0] += a.w * b.x; acc[3][1] += a.w * b.y; acc[3][2] += a.w * b.z; acc[3][3] += a.w * b.w;
            }
        }
        u16* dh = isM ? Mh : Wch;
#pragma unroll
        for (int i = 0; i < 4; ++i)
#pragma unroll
            for (int j = 0; j < 4; ++j) {
                const int a = bm + ty * 4 + i;      // k index
                const int n = bn + tx * 4 + j;      // n index
                dh[(size_t)n * 512 + a] = rne_bf16(acc[i][j]);
            }
    } else {
        const int n0 = (bx - 128) * 32;
        const int nl = tid & 31, jg = tid >> 5;
        float partial = 0.f;
        for (int s = 0; s < 64; ++s) {
            int j = jg + 8 * s;
            partial += bvec[j] * Wo[(size_t)j * 512 + n0 + nl];
        }
        red[jg][nl] = partial;
        __syncthreads();
        if (tid < 32) {
            float s2 = 0.f;
            for (int r2 = 0; r2 < 8; ++r2) s2 += red[r2][tid];
            bc[n0 + tid] = s2 + bo[n0 + tid];
        }
    }
}

// ============ stream_conv: coalesced keys-transpose (1024) + Q convert (2048) + V convert (2048) ============
// Transpose tiles: 64 d x 256 l. Read: wave = 4 rows x 256B contiguous. Write: wave = one
// channel row x 512B contiguous. LDS bf16 [64][264] (2-way conflicts only).
__global__ __launch_bounds__(256) void stream_conv(const float* __restrict__ keys, u16* __restrict__ Ktb,
                                                   const float* __restrict__ queries, u16* __restrict__ Qb,
                                                   const float* __restrict__ values, u16* __restrict__ Vb) {
    __shared__ __align__(16) u16 Ts[64 * 264];  // 33 KB
    const int bx = blockIdx.x;
    const int tid = threadIdx.x;
    if (bx < 1024) {
        const int db = (bx & 7) * 64;           // d-tile base
        const int lb = (bx >> 3) * 256;         // l-tile base (row in [ML])
        const int rr = tid >> 4;                // 0..15
        const int c4 = (tid & 15) * 4;          // d_local base
#pragma unroll
        for (int it = 0; it < 16; ++it) {
            const int r = it * 16 + rr;         // 0..255
            float4 v = *(const float4*)&keys[(size_t)(lb + r) * 512 + db + c4];
            Ts[(c4 + 0) * 264 + r] = rne_bf16(v.x);
            Ts[(c4 + 1) * 264 + r] = rne_bf16(v.y);
            Ts[(c4 + 2) * 264 + r] = rne_bf16(v.z);
            Ts[(c4 + 3) * 264 + r] = rne_bf16(v.w);
        }
        __syncthreads();
        const int wv = tid >> 6;                // 0..3
        const int ln = tid & 63;
#pragma unroll
        for (int it = 0; it < 16; ++it) {
            const int dl = it * 4 + wv;         // 0..63
            ushort4 o = *(const ushort4*)&Ts[dl * 264 + ln * 4];
            *(ushort4*)&Ktb[(size_t)(db + dl) * ML + lb + ln * 4] = o;
        }
    } else if (bx < 1024 + 2048) {
        const int idx = bx - 1024;
        const size_t base0 = (size_t)idx * 8192 + tid * 8;
#pragma unroll
        for (int it = 0; it < 4; ++it) {
            const size_t base = base0 + it * 2048;
            float4 f0 = *(const float4*)&queries[base];
            float4 f1 = *(const float4*)&queries[base + 4];
            *(uint4*)&Qb[base] = cvt8(f0, f1);
        }
    } else {
        const int idx = bx - (1024 + 2048);
        const size_t base0 = (size_t)idx * 8192 + tid * 8;
#pragma unroll
        for (int it = 0; it < 4; ++it) {
            const size_t base = base0 + it * 2048;
            float4 f0 = *(const float4*)&values[base];
            float4 f1 = *(const float4*)&values[base + 4];
            *(uint4*)&Vb[base] = cvt8(f0, f1);
        }
    }
}

// 4-way split reduce: grid (9, BB, 4); block z sums groups [z*64, z*64+64)
__global__ __launch_bounds__(256) void reduce_ppart(const float2* __restrict__ Pp,
                                                    float2* __restrict__ Pred4) {
    const int j = blockIdx.x * 256 + threadIdx.x;
    const int b = blockIdx.y;
    const int z = blockIdx.z;
    if (j > 2048) return;
    float sr = 0.f, si = 0.f;
    const float2* base = Pp + (size_t)b * NGRP * PPH + j;
    for (int g = z * 64; g < z * 64 + 64; ++g) {
        float2 p = base[(size_t)g * PPH];
        sr += p.x;
        si += p.y;
    }
    Pred4[((size_t)z * BB + b) * PPH + j] = make_float2(sr, si);
}

// 8 blocks: sum 4 partials + Hermitian reconstruction + inverse FFT (conj->fwd->Re), scaled
__global__ __launch_bounds__(256) void ifft_mean(const float2* __restrict__ Pred4,
                                                 float* __restrict__ mv) {
    __shared__ float lre[4096];
    __shared__ float lim[4096];
    constexpr int REV16[16] = {0, 8, 4, 12, 2, 10, 6, 14, 1, 9, 5, 13, 3, 11, 7, 15};
    const int t = threadIdx.x;
    const int b = blockIdx.x;
    for (int j = t; j < 4096; j += 256) {
        const int jj = (j <= 2048) ? j : 4096 - j;
        float sr = 0.f, si = 0.f;
#pragma unroll
        for (int z = 0; z < 4; ++z) {
            float2 p = Pred4[((size_t)z * BB + b) * PPH + jj];
            sr += p.x;
            si += p.y;
        }
        if (j > 2048) si = -si;  // Hermitian mirror
        int key = (j >> 8) & 15;
        int ph = j ^ ((key & 3) << 2) ^ ((key & 1) << 4);
        lre[ph] = sr;
        lim[ph] = -si;  // conj for inverse transform
    }
    __syncthreads();
    float ozr[16], ozi[16];
    fft4096_r16_core<false>(lre, lim, t, ozr, ozi);
    const float scale = 1.0f / (4096.0f * 512.0f);
#pragma unroll
    for (int i = 0; i < 16; ++i)
        mv[(size_t)b * 4096 + t + 256 * i] = ozr[REV16[i]] * scale;
}

// single block, 1024 threads: batch-mean, iterative top-8 argmax via shfl, per-batch softmax
__global__ __launch_bounds__(1024) void topk_softmax(const float* __restrict__ mv,
                                                     int* __restrict__ idxO,
                                                     float* __restrict__ tcO) {
    __shared__ float vals[4096];
    __shared__ float wv[16];
    __shared__ int wix[16];
    __shared__ int sidx[TOPK];
    const int tid = threadIdx.x;
    const int lane = tid & 63, wvid = tid >> 6;
    for (int j = tid; j < 4096; j += 1024) {
        float s = 0.f;
        for (int b = 0; b < BB; ++b) s += mv[(size_t)b * 4096 + j];
        vals[j] = s * 0.125f;
    }
    __syncthreads();
    for (int k = 0; k < TOPK; ++k) {
        float best = -INFINITY;
        int bi = 0x7fffffff;
        for (int j = tid; j < 4096; j += 1024) {
            float v = vals[j];
            if (v > best) { best = v; bi = j; }
        }
#pragma unroll
        for (int off = 32; off > 0; off >>= 1) {
            float ov = __shfl_down(best, off);
            int oi = __shfl_down(bi, off);
            if (ov > best || (ov == best && oi < bi)) { best = ov; bi = oi; }
        }
        if (lane == 0) { wv[wvid] = best; wix[wvid] = bi; }
        __syncthreads();
        if (wvid == 0) {
            best = (lane < 16) ? wv[lane] : -INFINITY;
            bi = (lane < 16) ? wix[lane] : 0x7fffffff;
#pragma unroll
            for (int off = 8; off > 0; off >>= 1) {
                float ov = __shfl_down(best, off);
                int oi = __shfl_down(bi, off);
                if (ov > best || (ov == best && oi < bi)) { best = ov; bi = oi; }
            }
            if (lane == 0) {
                sidx[k] = bi;
                idxO[k] = bi;
                vals[bi] = -INFINITY;
            }
        }
        __syncthreads();
    }
    if (tid < BB) {
        float w[TOPK];
        float m = -INFINITY;
        for (int k = 0; k < TOPK; ++k) {
            w[k] = mv[(size_t)tid * 4096 + sidx[k]];
            m = fmaxf(m, w[k]);
        }
        float s = 0.f;
        for (int k = 0; k < TOPK; ++k) { w[k] = expf(w[k] - m); s += w[k]; }
        float inv = 1.0f / s;
        for (int k = 0; k < TOPK; ++k) tcO[tid * TOPK + k] = w[k] * inv;
    }
}

// out[b,l,:] = sum_k tc[b,k] * VO_bf16[b,(l+idx[k])%L,:]
__global__ __launch_bounds__(256) void gather_out(const u16* __restrict__ VO,
                                                  const int* __restrict__ idx,
                                                  const float* __restrict__ tc,
                                                  float* __restrict__ out) {
    const int e = blockIdx.x * 256 + threadIdx.x;
    const int d8 = e & 63;
    const int l = (e >> 6) & 4095;
    const int b = e >> 18;
    float s[8] = {};
#pragma unroll
    for (int k = 0; k < TOPK; ++k) {
        const int src = (l + idx[k]) & 4095;
        const float w = tc[b * TOPK + k];
        uint4 v = *(const uint4*)&VO[((size_t)(b * 4096 + src)) * 512 + d8 * 8];
        s[0] += w * __uint_as_float(v.x << 16);
        s[1] += w * __uint_as_float(v.x & 0xFFFF0000u);
        s[2] += w * __uint_as_float(v.y << 16);
        s[3] += w * __uint_as_float(v.y & 0xFFFF0000u);
        s[4] += w * __uint_as_float(v.z << 16);
        s[5] += w * __uint_as_float(v.z & 0xFFFF0000u);
        s[6] += w * __uint_as_float(v.w << 16);
        s[7] += w * __uint_as_float(v.w & 0xFFFF0000u);
    }
    const size_t ob = ((size_t)(b * 4096 + l)) * 512 + d8 * 8;
    *(float4*)&out[ob]     = make_float4(s[0], s[1], s[2], s[3]);
    *(float4*)&out[ob + 4] = make_float4(s[4], s[5], s[6], s[7]);
}

extern "C" void kernel_launch(void* const* d_in, const int* in_sizes, int n_in,
                              void* d_out, int out_size, void* d_ws, size_t ws_size,
                              hipStream_t stream) {
    const float* queries = (const float*)d_in[0];
    const float* keys    = (const float*)d_in[1];
    const float* values  = (const float*)d_in[2];
    const float* Wq = (const float*)d_in[3];
    const float* Wk = (const float*)d_in[5];
    const float* Wv = (const float*)d_in[7];
    const float* bv = (const float*)d_in[8];
    const float* Wo = (const float*)d_in[9];
    const float* bo = (const float*)d_in[10];
    float* out = (float*)d_out;

    const size_t SZ = (size_t)ML * DMODEL;  // 16,777,216 elements
    u16* Qb  = (u16*)d_ws;                  // bf16 queries [ML][512]  32 MB
    u16* Vb  = Qb + SZ;                     // bf16 values             32 MB
    u16* Qtb = Vb + SZ;                     // bf16 q''^T [512][ML]    32 MB
    u16* Ktb = Qtb + SZ;                    // bf16 keys^T             32 MB
    u16* VOb = Ktb + SZ;                    // bf16 VO [ML][512]       32 MB
    float* Pp    = (float*)(VOb + SZ);      // 33.6 MB
    float* Pred4 = Pp + (size_t)BB * NGRP * PPH * 2;   // 4*BB*PPH*2 floats
    float* mv    = Pred4 + (size_t)4 * BB * PPH * 2;
    int*   idx   = (int*)(mv + 32768);
    float* tc    = mv + 32768 + 16;
    float* bc    = mv + 32768 + 96;
    u16* Mh  = (u16*)(bc + 512);            // 512 KB
    u16* Wch = Mh + 262144;                 // 512 KB

    dim3 blk(256);

    // 1) weight prep (small, independent)
    prep_weights<<<dim3(144), blk, 0, stream>>>(Wq, Wk, Wv, Wo, bv, bo, Mh, Wch, bc);

    // 2) streaming: coalesced keys-transpose + Q/V bf16 conversion
    stream_conv<<<dim3(1024 + 4096), blk, 0, stream>>>(keys, Ktb, queries, Qb, values, Vb);

    // 3) both GEMMs, pure global_load_lds staging (bf16 x bf16)
    gemm2<<<dim3(2048), blk, 0, stream>>>(Qb, Mh, Qtb, Vb, Wch, bc, VOb);

    // 4) correlation FFT (bf16 inputs, Hermitian half-spectrum, half writeback)
    fft_cross<<<dim3(BB * NGRP), blk, 0, stream>>>(Qtb, Ktb, Pp);

    // 5) spectrum reduce (4-way split over groups)
    reduce_ppart<<<dim3(9, BB, 4), blk, 0, stream>>>((const float2*)Pp, (float2*)Pred4);

    // 6) inverse FFT per batch (sums the 4 partials)
    ifft_mean<<<dim3(BB), blk, 0, stream>>>((const float2*)Pred4, mv);

    // 7) top-k + softmax
    topk_softmax<<<dim3(1), dim3(1024), 0, stream>>>(mv, idx, tc);

    // 8) weighted gather to output
    gather_out<<<dim3((BB * LSEQ * (DMODEL / 8)) / 256), blk, 0, stream>>>(VOb, idx, tc, out);
}

// Round 18
// 222.216 us; speedup vs baseline: 1.1344x; 1.1344x over previous
//
#include <hip/hip_runtime.h>
#include <math.h>

#define LSEQ 4096
#define DMODEL 512
#define BB 8
#define TOPK 8
#define ML (BB * LSEQ)          // 32768 rows
#define FFT_CH 2                // channels per fft_cross block
#define NGRP (DMODEL / FFT_CH)  // 256 groups per batch
#define PPH 2052                // float2 stride of half-spectrum (2049 used, padded)

typedef unsigned short u16;
typedef unsigned int u32;
typedef float f32x4 __attribute__((ext_vector_type(4)));
typedef short s16x8 __attribute__((ext_vector_type(8)));
typedef u16 u16x8 __attribute__((ext_vector_type(8)));

__device__ __forceinline__ u16 rne_bf16(float f) {
    u32 u = __float_as_uint(f);
    return (u16)((u + 0x7FFF + ((u >> 16) & 1)) >> 16);
}

// pack 8 fp32 (two float4) -> 8 RNE bf16 as uint4
__device__ __forceinline__ uint4 cvt8(const float4 f0, const float4 f1) {
    float fs[8] = {f0.x, f0.y, f0.z, f0.w, f1.x, f1.y, f1.z, f1.w};
    u32 h[4];
#pragma unroll
    for (int p = 0; p < 4; ++p) {
        u32 u0 = __float_as_uint(fs[2 * p]);
        u32 u1 = __float_as_uint(fs[2 * p + 1]);
        u32 h0 = u0 + 0x7FFF + ((u0 >> 16) & 1);
        u32 h1 = u1 + 0x7FFF + ((u1 >> 16) & 1);
        h[p] = __builtin_amdgcn_perm(h1, h0, 0x07060302u);
    }
    return make_uint4(h[0], h[1], h[2], h[3]);
}

#if defined(__has_builtin)
#if __has_builtin(__builtin_amdgcn_global_load_lds)
#define HAVE_GLL 1
#endif
#endif

// async 16B global->LDS; lbase is WAVE-UNIFORM, HW writes lbase + lane*16B.
__device__ __forceinline__ void gload_lds16(const u16* g, u16* lbase, int lane) {
#ifdef HAVE_GLL
    __builtin_amdgcn_global_load_lds((const __attribute__((address_space(1))) void*)g,
                                     (__attribute__((address_space(3))) void*)lbase, 16, 0, 0);
#else
    *(uint4*)(lbase + lane * 8) = *(const uint4*)g;
#endif
}

// ==================== 16-pt FFT, fully unrolled DIF (output bit-reversed in regs) ====================
__device__ __forceinline__ void fft16(float (&zr)[16], float (&zi)[16]) {
    const float C1 = 0.92387953251128674f, S1 = 0.38268343236508978f, R2 = 0.70710678118654752f;
#define BF0(i, j) { float ar=zr[i],ai=zi[i],br=zr[j],bi=zi[j]; zr[i]=ar+br; zi[i]=ai+bi; zr[j]=ar-br; zi[j]=ai-bi; }
#define BFW(i, j, wr, wi) { float ar=zr[i],ai=zi[i],br=zr[j],bi=zi[j]; zr[i]=ar+br; zi[i]=ai+bi; float dr=ar-br, di=ai-bi; zr[j]=dr*(wr)-di*(wi); zi[j]=dr*(wi)+di*(wr); }
#define BFI(i, j) { float ar=zr[i],ai=zi[i],br=zr[j],bi=zi[j]; zr[i]=ar+br; zi[i]=ai+bi; float dr=ar-br, di=ai-bi; zr[j]=di; zi[j]=-dr; }
    BF0(0, 8); BFW(1, 9, C1, -S1); BFW(2, 10, R2, -R2); BFW(3, 11, S1, -C1);
    BFI(4, 12); BFW(5, 13, -S1, -C1); BFW(6, 14, -R2, -R2); BFW(7, 15, -C1, -S1);
    BF0(0, 4); BFW(1, 5, R2, -R2); BFI(2, 6); BFW(3, 7, -R2, -R2);
    BF0(8, 12); BFW(9, 13, R2, -R2); BFI(10, 14); BFW(11, 15, -R2, -R2);
    BF0(0, 2); BFI(1, 3); BF0(4, 6); BFI(5, 7);
    BF0(8, 10); BFI(9, 11); BF0(12, 14); BFI(13, 15);
    BF0(0, 1); BF0(2, 3); BF0(4, 5); BF0(6, 7);
    BF0(8, 9); BF0(10, 11); BF0(12, 13); BF0(14, 15);
#undef BF0
#undef BFW
#undef BFI
}

// 3-level radix-16 4096-pt FFT core, chained twiddles. Phys-swizzled input.
// WRITEBACK: writes ONLY the upper half-spectrum (Z[2048..4095], slots REV16[odd]) to LDS
// in natural order — that's all the Hermitian mirror reads need.
template <bool WRITEBACK>
__device__ __forceinline__ void fft4096_r16_core(float* __restrict__ lre, float* __restrict__ lim, int t,
                                                 float (&ozr)[16], float (&ozi)[16]) {
    constexpr int REV16[16] = {0, 8, 4, 12, 2, 10, 6, 14, 1, 9, 5, 13, 3, 11, 7, 15};
    float zr[16], zi[16];
#pragma unroll
    for (int gg = 0; gg < 16; ++gg) {
        int n = 256 * gg + t;
        int p = n ^ ((gg & 3) << 2) ^ ((gg & 1) << 4);
        zr[gg] = lre[p]; zi[gg] = lim[p];
    }
    fft16(zr, zi);
    {
        const int n1 = t >> 4;
        float w1i, w1r;
        __sincosf(-0.0245436926061702596f * (float)n1, &w1i, &w1r);  // -pi/128 * n1
        float wr = 1.f, wi = 0.f;
#pragma unroll
        for (int k0 = 0; k0 < 16; ++k0) {
            float vr = zr[REV16[k0]], vi = zi[REV16[k0]];
            if (k0) {
                float nr = wr * w1r - wi * w1i;
                wi = wr * w1i + wi * w1r;
                wr = nr;
                float tr = vr * wr - vi * wi;
                vi = vr * wi + vi * wr;
                vr = tr;
            }
            int n = 256 * k0 + t;
            int p = n ^ ((k0 & 3) << 2) ^ ((k0 & 1) << 4);
            lre[p] = vr; lim[p] = vi;
        }
    }
    __syncthreads();
    {
        const int k0 = t >> 4, n2 = t & 15;
        const int x0 = ((k0 & 3) << 2) | ((k0 & 1) << 4);
#pragma unroll
        for (int gg = 0; gg < 16; ++gg) {
            int n = 256 * k0 + 16 * gg + n2;
            zr[gg] = lre[n ^ x0]; zi[gg] = lim[n ^ x0];
        }
        fft16(zr, zi);
        float wbi, wbr, wsi, wsr;
        __sincosf(-0.00153398078788564123f * (float)(n2 * k0), &wbi, &wbr);  // -pi/2048 * n2*k0
        __sincosf(-0.0245436926061702596f * (float)n2, &wsi, &wsr);          // -pi/128 * n2
        float wr = wbr, wi = wbi;
#pragma unroll
        for (int k1 = 0; k1 < 16; ++k1) {
            float vr = zr[REV16[k1]], vi = zi[REV16[k1]];
            if (k1) {
                float nr = wr * wsr - wi * wsi;
                wi = wr * wsi + wi * wsr;
                wr = nr;
            }
            float tr = vr * wr - vi * wi;
            vi = vr * wi + vi * wr;
            vr = tr;
            int n = 256 * k0 + 16 * k1 + n2;
            lre[n ^ x0] = vr; lim[n ^ x0] = vi;
        }
    }
    __syncthreads();
    {
        const int k0 = t & 15, k1 = t >> 4;
        const int nb4 = 64 * k0 + 4 * k1;
        const int xv = (k0 & 3) | ((k0 & 1) << 2);
#pragma unroll
        for (int i = 0; i < 4; ++i) {
            int p4 = (nb4 + i) ^ xv;
            float4 fr = *(const float4*)&lre[4 * p4];
            float4 fi = *(const float4*)&lim[4 * p4];
            ozr[4 * i + 0] = fr.x; ozr[4 * i + 1] = fr.y; ozr[4 * i + 2] = fr.z; ozr[4 * i + 3] = fr.w;
            ozi[4 * i + 0] = fi.x; ozi[4 * i + 1] = fi.y; ozi[4 * i + 2] = fi.z; ozi[4 * i + 3] = fi.w;
        }
        fft16(ozr, ozi);
        if constexpr (WRITEBACK) {
            __syncthreads();  // phys reads done before natural-order overwrite
#pragma unroll
            for (int r = 1; r < 16; r += 2) {   // REV16[odd] -> Z[>=2048]
                const int k2 = REV16[r];
                lre[t + 256 * k2] = ozr[r];
                lim[t + 256 * k2] = ozi[r];
            }
            __syncthreads();
        }
    }
}

// grid: BB*NGRP blocks; block (b,g): channels d = g*FFT_CH..+1.  bf16 inputs.
__global__ __launch_bounds__(256) void fft_cross(const u16* __restrict__ Qtb,
                                                 const u16* __restrict__ Ktb,
                                                 float* __restrict__ Ppart) {
    __shared__ float lre[4096];
    __shared__ float lim[4096];
    constexpr int REV16[16] = {0, 8, 4, 12, 2, 10, 6, 14, 1, 9, 5, 13, 3, 11, 7, 15};
    const int t = threadIdx.x;
    const int b = blockIdx.x / NGRP;
    const int g = blockIdx.x % NGRP;

    float2 acc[8];
#pragma unroll
    for (int i = 0; i < 8; ++i) acc[i] = make_float2(0.f, 0.f);
    float accn = 0.f;  // Nyquist bin (j=2048), real

    const uint4* q8 = (const uint4*)(Qtb + (size_t)(g * FFT_CH) * ML + (size_t)b * LSEQ);
    const uint4* k8 = (const uint4*)(Ktb + (size_t)(g * FFT_CH) * ML + (size_t)b * LSEQ);

    uint4 pq[2], pk[2];
    pq[0] = q8[t]; pq[1] = q8[t + 256];
    pk[0] = k8[t]; pk[1] = k8[t + 256];

    for (int c = 0; c < FFT_CH; ++c) {
        __syncthreads();  // prev channel's mirror-reads done
#pragma unroll
        for (int i = 0; i < 2; ++i) {
            const int u = t + 256 * i;          // uint4 index (8 bf16)
            const uint4 vq = pq[i], vk = pk[i];
#pragma unroll
            for (int hh = 0; hh < 2; ++hh) {
                const int v = 2 * u + hh;       // float4-block index
                const int key = (v >> 6) & 15;
                const int p4 = v ^ (key & 3) ^ ((key & 1) << 2);
                const u32 w0 = hh ? vq.z : vq.x;
                const u32 w1 = hh ? vq.w : vq.y;
                float4 fa = make_float4(__uint_as_float(w0 << 16), __uint_as_float(w0 & 0xFFFF0000u),
                                        __uint_as_float(w1 << 16), __uint_as_float(w1 & 0xFFFF0000u));
                *(float4*)&lre[4 * p4] = fa;
                const u32 x0 = hh ? vk.z : vk.x;
                const u32 x1 = hh ? vk.w : vk.y;
                float4 fb4 = make_float4(__uint_as_float(x0 << 16), __uint_as_float(x0 & 0xFFFF0000u),
                                         __uint_as_float(x1 << 16), __uint_as_float(x1 & 0xFFFF0000u));
                *(float4*)&lim[4 * p4] = fb4;
            }
        }
        if (c + 1 < FFT_CH) {
            const uint4* qn = q8 + (size_t)(c + 1) * (ML / 8);
            const uint4* kn = k8 + (size_t)(c + 1) * (ML / 8);
            pq[0] = qn[t]; pq[1] = qn[t + 256];
            pk[0] = kn[t]; pk[1] = kn[t + 256];
        }
        __syncthreads();
        float ozr[16], ozi[16];
        fft4096_r16_core<true>(lre, lim, t, ozr, ozi);
        // cross-spectrum: own bins from registers, mirror bins (upper half) from LDS
#pragma unroll
        for (int i = 0; i < 8; ++i) {
            const int j = i * 256 + t;
            const int nj = (4096 - j) & 4095;
            const int r = REV16[i];
            float zfr = ozr[r], zfi = ozi[r];
            float znr, zni;
            if (j) { znr = lre[nj]; zni = lim[nj]; }
            else   { znr = zfr;     zni = zfi;     }   // Z[0] is its own mirror
            float qr = 0.5f * (zfr + znr);
            float qi = 0.5f * (zfi - zni);
            float kr = 0.5f * (zfi + zni);
            float ki = -0.5f * (zfr - znr);
            acc[i].x += qr * kr + qi * ki;
            acc[i].y += qi * kr - qr * ki;
        }
        if (t == 0) accn += ozr[1] * ozi[1];  // bin 2048 = slot REV16[8]=1 of thread 0
    }
    float2* Pp = (float2*)Ppart + (size_t)blockIdx.x * PPH;
#pragma unroll
    for (int i = 0; i < 8; ++i) Pp[i * 256 + t] = acc[i];
    if (t == 0) Pp[2048] = make_float2(accn, 0.f);
}

// ============ m97-style bf16 MFMA GEMM: A,B both bf16 -> pure global_load_lds staging ============
template <bool TOUT, bool BIAS>
__device__ __forceinline__ void gemm_bf16_body(const u16* __restrict__ A,
                                               const u16* __restrict__ B,
                                               const float* __restrict__ bias,
                                               u16* __restrict__ Cv, int lin, int tid,
                                               u16* sA, u16* sB) {
    const int t = (lin & 7) * 128 + (lin >> 3);   // XCD-chunked swizzle (1024 blocks)
    const int bm = (t >> 2) * 128;
    const int bn = (t & 3) * 128;
    const int lane = tid & 63, wid = tid >> 6;
    const int wm = wid >> 1, wn = wid & 1;
    const int l15 = lane & 15, kg = lane >> 4;

    const int srow = lane >> 3, sc = lane & 7;    // staging: 8 rows x 8 chunks per issue

    f32x4 acc[4][4] = {};

    for (int k0 = 0; k0 < 512; k0 += 64) {
        __syncthreads();  // prev compute's ds_reads done; LDS free
#pragma unroll
        for (int i = 0; i < 4; ++i) {
            const int grp = wid * 4 + i;          // 0..15, 8 rows each
            const int row = 8 * grp + srow;
            gload_lds16(A + (size_t)(bm + row) * 512 + k0 + ((sc ^ (row & 7)) << 3),
                        sA + grp * 512, lane);
        }
#pragma unroll
        for (int i = 0; i < 4; ++i) {
            const int grp = wid * 4 + i;
            const int row = 8 * grp + srow;
            gload_lds16(B + (size_t)(bn + row) * 512 + k0 + ((sc ^ (row & 7)) << 3),
                        sB + grp * 512, lane);
        }
        __syncthreads();  // drains vmcnt -> async loads landed
#pragma unroll
        for (int kk = 0; kk < 2; ++kk) {
            const int cb = kk * 4 + kg;
            s16x8 af[4], bf[4];
#pragma unroll
            for (int mi = 0; mi < 4; ++mi) {
                const int row = wm * 64 + mi * 16 + l15;
                af[mi] = *(const s16x8*)&sA[row * 64 + (((cb ^ (row & 7))) << 3)];
            }
#pragma unroll
            for (int ni = 0; ni < 4; ++ni) {
                const int row = wn * 64 + ni * 16 + l15;
                bf[ni] = *(const s16x8*)&sB[row * 64 + (((cb ^ (row & 7))) << 3)];
            }
#pragma unroll
            for (int ni = 0; ni < 4; ++ni)
#pragma unroll
                for (int mi = 0; mi < 4; ++mi)
                    acc[mi][ni] = __builtin_amdgcn_mfma_f32_16x16x32_bf16(af[mi], bf[ni], acc[mi][ni], 0, 0, 0);
        }
    }
    // epilogue (C/D layout: col = lane&15, row = (lane>>4)*4 + reg)
    if constexpr (TOUT) {
#pragma unroll
        for (int ni = 0; ni < 4; ++ni) {
            const int d = bn + wn * 64 + ni * 16 + l15;
#pragma unroll
            for (int mi = 0; mi < 4; ++mi) {
                const int rb = bm + wm * 64 + mi * 16 + (kg << 2);
                ushort4 o;
                o.x = rne_bf16(acc[mi][ni][0]); o.y = rne_bf16(acc[mi][ni][1]);
                o.z = rne_bf16(acc[mi][ni][2]); o.w = rne_bf16(acc[mi][ni][3]);
                *(ushort4*)&Cv[(size_t)d * ML + rb] = o;
            }
        }
    } else {
#pragma unroll
        for (int ni = 0; ni < 4; ++ni) {
            const int col = bn + wn * 64 + ni * 16 + l15;
            const float bvv = BIAS ? bias[col] : 0.0f;
#pragma unroll
            for (int mi = 0; mi < 4; ++mi) {
                const int rb = bm + wm * 64 + mi * 16 + (kg << 2);
#pragma unroll
                for (int r = 0; r < 4; ++r)
                    Cv[(size_t)(rb + r) * 512 + col] = rne_bf16(acc[mi][ni][r] + bvv);
            }
        }
    }
}

// ============ gemm2: Q-GEMM (1024) + V-GEMM (1024), 1:1 interleave ============
__global__ __launch_bounds__(256) void gemm2(const u16* __restrict__ Qb,
                                             const u16* __restrict__ Mh, u16* __restrict__ Qtb,
                                             const u16* __restrict__ Vb,
                                             const u16* __restrict__ Wch, const float* __restrict__ bc,
                                             u16* __restrict__ VOb) {
    __shared__ __align__(16) u16 smem[16384];  // 32 KB
    const int g = blockIdx.x;
    const int q = g >> 1, r = g & 1;
    if (r == 0)
        gemm_bf16_body<true, false>(Qb, Mh, nullptr, Qtb, q, threadIdx.x, smem, smem + 8192);
    else
        gemm_bf16_body<false, true>(Vb, Wch, bc, VOb, q, threadIdx.x, smem, smem + 8192);
}

// ============ prep_stream: weights(144) + keys-transpose(4096) + Q/V convert (2048+2048, x4 grid-stride) ============
__global__ __launch_bounds__(256) void prep_stream(const float* __restrict__ Wq, const float* __restrict__ Wk,
                                                   const float* __restrict__ Wv, const float* __restrict__ Wo,
                                                   const float* __restrict__ bvec, const float* __restrict__ bo,
                                                   u16* __restrict__ Mh, u16* __restrict__ Wch,
                                                   float* __restrict__ bc,
                                                   const float* __restrict__ keys, u16* __restrict__ Ktb,
                                                   const float* __restrict__ queries, u16* __restrict__ Qb,
                                                   const float* __restrict__ values, u16* __restrict__ Vb) {
    __shared__ __align__(16) char smem[16896];
    const int bx = blockIdx.x;
    const int tid = threadIdx.x;
    if (bx < 128) {
        float (*As)[64] = (float (*)[64])smem;
        float (*Ws)[64] = (float (*)[64])(smem + 4096);
        const bool isM = bx < 64;
        const int id = bx & 63;
        const int bm = (id >> 3) * 64, bn = (id & 7) * 64;
        const int tx = tid & 15, ty = tid >> 4;
        float acc[4][4] = {};
        const int arow = tid >> 2, ak4 = tid & 3;
        const int wrow = tid >> 4, wc4 = tid & 15;
        const float* Abase = isM ? Wq : Wv;
        for (int k0 = 0; k0 < 512; k0 += 16) {
            float4 av = *(const float4*)&Abase[(size_t)(bm + arow) * 512 + k0 + ak4 * 4];
            float4 wv4;
            if (isM) wv4 = *(const float4*)&Wk[(size_t)(bn + arow) * 512 + k0 + ak4 * 4];
            else     wv4 = *(const float4*)&Wo[(size_t)(k0 + wrow) * 512 + bn + wc4 * 4];
            __syncthreads();
            As[ak4 * 4 + 0][arow] = av.x;
            As[ak4 * 4 + 1][arow] = av.y;
            As[ak4 * 4 + 2][arow] = av.z;
            As[ak4 * 4 + 3][arow] = av.w;
            if (isM) {
                Ws[ak4 * 4 + 0][arow] = wv4.x;
                Ws[ak4 * 4 + 1][arow] = wv4.y;
                Ws[ak4 * 4 + 2][arow] = wv4.z;
                Ws[ak4 * 4 + 3][arow] = wv4.w;
            } else {
                *(float4*)&Ws[wrow][wc4 * 4] = wv4;
            }
            __syncthreads();
#pragma unroll
            for (int k = 0; k < 16; ++k) {
                float4 a = *(const float4*)&As[k][ty * 4];
                float4 b = *(const float4*)&Ws[k][tx * 4];
                acc[0][0] += a.x * b.x; acc[0][1] += a.x * b.y; acc[0][2] += a.x * b.z; acc[0][3] += a.x * b.w;
                acc[1][0] += a.y * b.x; acc[1][1] += a.y * b.y; acc[1][2] += a.y * b.z; acc[1][3] += a.y * b.w;
                acc[2][0] += a.z * b.x; acc[2][1] += a.z * b.y; acc[2][2] += a.z * b.z; acc[2][3] += a.z * b.w;
                acc[3][0] += a.w * b.x; acc[3][1] += a.w * b.y; acc[3][2] += a.w * b.z; acc[3][3] += a.w * b.w;
            }
        }
        u16* dh = isM ? Mh : Wch;
#pragma unroll
        for (int i = 0; i < 4; ++i)
#pragma unroll
            for (int j = 0; j < 4; ++j) {
                const int a = bm + ty * 4 + i;      // k index
                const int n = bn + tx * 4 + j;      // n index
                dh[(size_t)n * 512 + a] = rne_bf16(acc[i][j]);
            }
    } else if (bx < 144) {
        float (*red)[32] = (float (*)[32])smem;
        const int n0 = (bx - 128) * 32;
        const int nl = tid & 31, jg = tid >> 5;
        float partial = 0.f;
        for (int s = 0; s < 64; ++s) {
            int j = jg + 8 * s;
            partial += bvec[j] * Wo[(size_t)j * 512 + n0 + nl];
        }
        red[jg][nl] = partial;
        __syncthreads();
        if (tid < 32) {
            float s2 = 0.f;
            for (int r2 = 0; r2 < 8; ++r2) s2 += red[r2][tid];
            bc[n0 + tid] = s2 + bo[n0 + tid];
        }
    } else if (bx < 144 + 4096) {
        // keys transpose -> bf16 Ktb [512][ML]
        float* Ts = (float*)smem;  // [64][65]
        const int tb = bx - 144;
        const int bd = (tb & 7) * 64;
        const int bm = (tb >> 3) * 64;
        const int rr = tid >> 2, c4 = tid & 3;
#pragma unroll
        for (int i = 0; i < 4; ++i) {
            const int c0 = (c4 + 4 * i) * 4;
            float4 v = *(const float4*)&keys[(size_t)(bm + rr) * DMODEL + bd + c0];
            Ts[rr * 65 + c0 + 0] = v.x; Ts[rr * 65 + c0 + 1] = v.y;
            Ts[rr * 65 + c0 + 2] = v.z; Ts[rr * 65 + c0 + 3] = v.w;
        }
        __syncthreads();
        const int dl = tid >> 2, m4 = tid & 3;
#pragma unroll
        for (int i = 0; i < 4; ++i) {
            const int m0 = (m4 + 4 * i) * 4;
            ushort4 o;
            o.x = rne_bf16(Ts[(m0 + 0) * 65 + dl]);
            o.y = rne_bf16(Ts[(m0 + 1) * 65 + dl]);
            o.z = rne_bf16(Ts[(m0 + 2) * 65 + dl]);
            o.w = rne_bf16(Ts[(m0 + 3) * 65 + dl]);
            *(ushort4*)&Ktb[(size_t)(bd + dl) * ML + bm + m0] = o;
        }
    } else if (bx < 144 + 4096 + 2048) {
        // queries -> bf16, 8192 floats/block (4 independent chunks -> 8 loads in flight)
        const int idx = bx - (144 + 4096);          // 0..2047
        const size_t base0 = (size_t)idx * 8192 + tid * 8;
#pragma unroll
        for (int it = 0; it < 4; ++it) {
            const size_t base = base0 + it * 2048;
            float4 f0 = *(const float4*)&queries[base];
            float4 f1 = *(const float4*)&queries[base + 4];
            *(uint4*)&Qb[base] = cvt8(f0, f1);
        }
    } else {
        // values -> bf16
        const int idx = bx - (144 + 4096 + 2048);   // 0..2047
        const size_t base0 = (size_t)idx * 8192 + tid * 8;
#pragma unroll
        for (int it = 0; it < 4; ++it) {
            const size_t base = base0 + it * 2048;
            float4 f0 = *(const float4*)&values[base];
            float4 f1 = *(const float4*)&values[base + 4];
            *(uint4*)&Vb[base] = cvt8(f0, f1);
        }
    }
}

// 4-way split reduce: grid (9, BB, 4); block z sums groups [z*64, z*64+64)
__global__ __launch_bounds__(256) void reduce_ppart(const float2* __restrict__ Pp,
                                                    float2* __restrict__ Pred4) {
    const int j = blockIdx.x * 256 + threadIdx.x;
    const int b = blockIdx.y;
    const int z = blockIdx.z;
    if (j > 2048) return;
    float sr = 0.f, si = 0.f;
    const float2* base = Pp + (size_t)b * NGRP * PPH + j;
    for (int g = z * 64; g < z * 64 + 64; ++g) {
        float2 p = base[(size_t)g * PPH];
        sr += p.x;
        si += p.y;
    }
    Pred4[((size_t)z * BB + b) * PPH + j] = make_float2(sr, si);
}

// 8 blocks: sum 4 partials + Hermitian reconstruction + inverse FFT (conj->fwd->Re), scaled
__global__ __launch_bounds__(256) void ifft_mean(const float2* __restrict__ Pred4,
                                                 float* __restrict__ mv) {
    __shared__ float lre[4096];
    __shared__ float lim[4096];
    constexpr int REV16[16] = {0, 8, 4, 12, 2, 10, 6, 14, 1, 9, 5, 13, 3, 11, 7, 15};
    const int t = threadIdx.x;
    const int b = blockIdx.x;
    for (int j = t; j < 4096; j += 256) {
        const int jj = (j <= 2048) ? j : 4096 - j;
        float sr = 0.f, si = 0.f;
#pragma unroll
        for (int z = 0; z < 4; ++z) {
            float2 p = Pred4[((size_t)z * BB + b) * PPH + jj];
            sr += p.x;
            si += p.y;
        }
        if (j > 2048) si = -si;  // Hermitian mirror
        int key = (j >> 8) & 15;
        int ph = j ^ ((key & 3) << 2) ^ ((key & 1) << 4);
        lre[ph] = sr;
        lim[ph] = -si;  // conj for inverse transform
    }
    __syncthreads();
    float ozr[16], ozi[16];
    fft4096_r16_core<false>(lre, lim, t, ozr, ozi);
    const float scale = 1.0f / (4096.0f * 512.0f);
#pragma unroll
    for (int i = 0; i < 16; ++i)
        mv[(size_t)b * 4096 + t + 256 * i] = ozr[REV16[i]] * scale;
}

// single block, 1024 threads: batch-mean, iterative top-8 argmax via shfl, per-batch softmax
__global__ __launch_bounds__(1024) void topk_softmax(const float* __restrict__ mv,
                                                     int* __restrict__ idxO,
                                                     float* __restrict__ tcO) {
    __shared__ float vals[4096];
    __shared__ float wv[16];
    __shared__ int wix[16];
    __shared__ int sidx[TOPK];
    const int tid = threadIdx.x;
    const int lane = tid & 63, wvid = tid >> 6;
    for (int j = tid; j < 4096; j += 1024) {
        float s = 0.f;
        for (int b = 0; b < BB; ++b) s += mv[(size_t)b * 4096 + j];
        vals[j] = s * 0.125f;
    }
    __syncthreads();
    for (int k = 0; k < TOPK; ++k) {
        float best = -INFINITY;
        int bi = 0x7fffffff;
        for (int j = tid; j < 4096; j += 1024) {
            float v = vals[j];
            if (v > best) { best = v; bi = j; }
        }
#pragma unroll
        for (int off = 32; off > 0; off >>= 1) {
            float ov = __shfl_down(best, off);
            int oi = __shfl_down(bi, off);
            if (ov > best || (ov == best && oi < bi)) { best = ov; bi = oi; }
        }
        if (lane == 0) { wv[wvid] = best; wix[wvid] = bi; }
        __syncthreads();
        if (wvid == 0) {
            best = (lane < 16) ? wv[lane] : -INFINITY;
            bi = (lane < 16) ? wix[lane] : 0x7fffffff;
#pragma unroll
            for (int off = 8; off > 0; off >>= 1) {
                float ov = __shfl_down(best, off);
                int oi = __shfl_down(bi, off);
                if (ov > best || (ov == best && oi < bi)) { best = ov; bi = oi; }
            }
            if (lane == 0) {
                sidx[k] = bi;
                idxO[k] = bi;
                vals[bi] = -INFINITY;
            }
        }
        __syncthreads();
    }
    if (tid < BB) {
        float w[TOPK];
        float m = -INFINITY;
        for (int k = 0; k < TOPK; ++k) {
            w[k] = mv[(size_t)tid * 4096 + sidx[k]];
            m = fmaxf(m, w[k]);
        }
        float s = 0.f;
        for (int k = 0; k < TOPK; ++k) { w[k] = expf(w[k] - m); s += w[k]; }
        float inv = 1.0f / s;
        for (int k = 0; k < TOPK; ++k) tcO[tid * TOPK + k] = w[k] * inv;
    }
}

// out[b,l,:] = sum_k tc[b,k] * VO_bf16[b,(l+idx[k])%L,:]
__global__ __launch_bounds__(256) void gather_out(const u16* __restrict__ VO,
                                                  const int* __restrict__ idx,
                                                  const float* __restrict__ tc,
                                                  float* __restrict__ out) {
    const int e = blockIdx.x * 256 + threadIdx.x;
    const int d8 = e & 63;
    const int l = (e >> 6) & 4095;
    const int b = e >> 18;
    float s[8] = {};
#pragma unroll
    for (int k = 0; k < TOPK; ++k) {
        const int src = (l + idx[k]) & 4095;
        const float w = tc[b * TOPK + k];
        uint4 v = *(const uint4*)&VO[((size_t)(b * 4096 + src)) * 512 + d8 * 8];
        s[0] += w * __uint_as_float(v.x << 16);
        s[1] += w * __uint_as_float(v.x & 0xFFFF0000u);
        s[2] += w * __uint_as_float(v.y << 16);
        s[3] += w * __uint_as_float(v.y & 0xFFFF0000u);
        s[4] += w * __uint_as_float(v.z << 16);
        s[5] += w * __uint_as_float(v.z & 0xFFFF0000u);
        s[6] += w * __uint_as_float(v.w << 16);
        s[7] += w * __uint_as_float(v.w & 0xFFFF0000u);
    }
    const size_t ob = ((size_t)(b * 4096 + l)) * 512 + d8 * 8;
    *(float4*)&out[ob]     = make_float4(s[0], s[1], s[2], s[3]);
    *(float4*)&out[ob + 4] = make_float4(s[4], s[5], s[6], s[7]);
}

extern "C" void kernel_launch(void* const* d_in, const int* in_sizes, int n_in,
                              void* d_out, int out_size, void* d_ws, size_t ws_size,
                              hipStream_t stream) {
    const float* queries = (const float*)d_in[0];
    const float* keys    = (const float*)d_in[1];
    const float* values  = (const float*)d_in[2];
    const float* Wq = (const float*)d_in[3];
    const float* Wk = (const float*)d_in[5];
    const float* Wv = (const float*)d_in[7];
    const float* bv = (const float*)d_in[8];
    const float* Wo = (const float*)d_in[9];
    const float* bo = (const float*)d_in[10];
    float* out = (float*)d_out;

    const size_t SZ = (size_t)ML * DMODEL;  // 16,777,216 elements
    u16* Qb  = (u16*)d_ws;                  // bf16 queries [ML][512]  32 MB
    u16* Vb  = Qb + SZ;                     // bf16 values             32 MB
    u16* Qtb = Vb + SZ;                     // bf16 q''^T [512][ML]    32 MB
    u16* Ktb = Qtb + SZ;                    // bf16 keys^T             32 MB
    u16* VOb = Ktb + SZ;                    // bf16 VO [ML][512]       32 MB
    float* Pp    = (float*)(VOb + SZ);      // 33.6 MB
    float* Pred4 = Pp + (size_t)BB * NGRP * PPH * 2;   // 4*BB*PPH*2 floats
    float* mv    = Pred4 + (size_t)4 * BB * PPH * 2;
    int*   idx   = (int*)(mv + 32768);
    float* tc    = mv + 32768 + 16;
    float* bc    = mv + 32768 + 96;
    u16* Mh  = (u16*)(bc + 512);            // 512 KB
    u16* Wch = Mh + 262144;                 // 512 KB

    dim3 blk(256);

    // 1) all-independent: weights + keys transpose + Q/V bf16 conversion (x4 grid-stride)
    prep_stream<<<dim3(144 + 4096 + 4096), blk, 0, stream>>>(
        Wq, Wk, Wv, Wo, bv, bo, Mh, Wch, bc, keys, Ktb, queries, Qb, values, Vb);

    // 2) both GEMMs, pure global_load_lds staging (bf16 x bf16)
    gemm2<<<dim3(2048), blk, 0, stream>>>(Qb, Mh, Qtb, Vb, Wch, bc, VOb);

    // 3) correlation FFT (bf16 inputs, Hermitian half-spectrum, half writeback)
    fft_cross<<<dim3(BB * NGRP), blk, 0, stream>>>(Qtb, Ktb, Pp);

    // 4) spectrum reduce (4-way split over groups)
    reduce_ppart<<<dim3(9, BB, 4), blk, 0, stream>>>((const float2*)Pp, (float2*)Pred4);

    // 5) inverse FFT per batch (sums the 4 partials)
    ifft_mean<<<dim3(BB), blk, 0, stream>>>((const float2*)Pred4, mv);

    // 6) top-k + softmax
    topk_softmax<<<dim3(1), dim3(1024), 0, stream>>>(mv, idx, tc);

    // 7) weighted gather to output
    gather_out<<<dim3((BB * LSEQ * (DMODEL / 8)) / 256), blk, 0, stream>>>(VOb, idx, tc, out);
}